// Round 1
// baseline (137.833 us; speedup 1.0000x reference)
//
#include <hip/hip_runtime.h>

#define HH 160
#define WW 160
#define DD 160
#define BB 4
#define NPB (HH * WW * DD / 4)   // 1,024,000 float4 per batch
#define K1B 256                   // min-pass blocks per batch

typedef float vfloat4 __attribute__((ext_vector_type(4)));

// ---- kernel 1: per-batch block-partial min (NO atomics) + affine constants ----
// grid (256, BB) x 256. Each thread reads 16 float4 (4 rounds, MLP=4),
// stride 65536 float4. Block partial min -> partial[b*256 + bx].
// Block (0, y=0) threads 0..3 also compute fp64 affine constants:
//   ix = R00*x + R01*y + R02*z + 79.5*(t0 - R00 - R01 - R02 + 1)
// (exact fold of linspace + cx scaling, since 79.5*(2/159) == 1).
__global__ __launch_bounds__(256) void min_cst_kernel(const float4* __restrict__ img4,
                                                      const float* __restrict__ transfos,
                                                      float* __restrict__ partial,
                                                      double* __restrict__ cst) {
    const int b = blockIdx.y;
    const size_t base = (size_t)b * NPB;
    const int t0 = blockIdx.x * 256 + threadIdx.x;   // < 65536
    const int S = K1B * 256;                          // 65536

    float m = 3.4e38f;
    #pragma unroll
    for (int r = 0; r < 4; r++) {
        const int i0 = t0 + 4 * r * S;
        float4 v0 = img4[base + i0];
        float4 v1 = img4[base + i0 + S];
        float4 v2 = img4[base + i0 + 2 * S];
        float4 v3 = make_float4(3.4e38f, 3.4e38f, 3.4e38f, 3.4e38f);
        if (i0 + 3 * S < NPB) v3 = img4[base + i0 + 3 * S];   // only r==3 can fail
        m = fminf(m, fminf(fminf(v0.x, v0.y), fminf(v0.z, v0.w)));
        m = fminf(m, fminf(fminf(v1.x, v1.y), fminf(v1.z, v1.w)));
        m = fminf(m, fminf(fminf(v2.x, v2.y), fminf(v2.z, v2.w)));
        m = fminf(m, fminf(fminf(v3.x, v3.y), fminf(v3.z, v3.w)));
    }

    #pragma unroll
    for (int o = 32; o >= 1; o >>= 1) m = fminf(m, __shfl_down(m, o));
    __shared__ float s[4];
    const int lane = threadIdx.x & 63, wid = threadIdx.x >> 6;
    if (lane == 0) s[wid] = m;
    __syncthreads();
    if (threadIdx.x == 0) {
        partial[b * K1B + blockIdx.x] =
            fminf(fminf(s[0], s[1]), fminf(s[2], s[3]));
    }

    // affine constants (fp64), once per batch, by block (0,0) threads 0..3
    if (blockIdx.x == 0 && blockIdx.y == 0 && threadIdx.x < BB) {
        const int bb = threadIdx.x;
        const float* q = transfos + bb * 7;
        double x = q[0], y = q[1], z = q[2], w = q[3];
        double tx = 2.0 * x, ty = 2.0 * y, tz = 2.0 * z;
        double twx = tx * w, twy = ty * w, twz = tz * w;
        double txx = tx * x, txy = ty * x, txz = tz * x;
        double tyy = ty * y, tyz = tz * y, tzz = tz * z;
        double R[3][3] = {
            {1.0 - (tyy + tzz), txy - twz,         txz + twy},
            {txy + twz,         1.0 - (txx + tzz), tyz - twx},
            {txz - twy,         tyz + twx,         1.0 - (txx + tyy)}
        };
        double t[3] = {(double)q[4], (double)q[5], (double)q[6]};
        for (int r = 0; r < 3; r++) {
            cst[bb * 12 + r * 4 + 0] = R[r][0];
            cst[bb * 12 + r * 4 + 1] = R[r][1];
            cst[bb * 12 + r * 4 + 2] = R[r][2];
            cst[bb * 12 + r * 4 + 3] = 79.5 * (t[r] - R[r][0] - R[r][1] - R[r][2] + 1.0);
        }
    }
}

// ---- kernel 2: affine map + trilinear gather, 3D-tiled ----
// Block (256 threads) covers an output tile of 8y x 8x x 16z:
//   tz = tid&3 (4 z-quads), tx = (tid>>2)&7, ty = tid>>5.
// A wave covers a compact 2y x 8x x 16z brick -> its gather footprint is a
// small rotated box (lanes share cache lines) instead of a 160-long line.
// Wave-level __any(valid) guard; inside, branchless unrolled k=0..3 so all
// 32 gather loads can be in flight at once. Invalid lanes load clamped
// border addresses and get cndmask'd to fill (bit-identical valid results).
// grid (DD/16=10, WW/8=20, (HH/8)*BB=80) x 256.
__global__ __launch_bounds__(256) void st3d_kernel(const float* __restrict__ img,
                                                   const double* __restrict__ cst,
                                                   const float* __restrict__ partial,
                                                   float* __restrict__ out) {
    const int bzc = blockIdx.z;
    const int b = bzc / 20;            // HH/8 = 20 y-tiles
    const int yt = bzc - b * 20;

    // ---- fill = min over this batch's 256 partials ----
    __shared__ float sred[4];
    float pm = partial[b * K1B + threadIdx.x];
    #pragma unroll
    for (int o = 32; o >= 1; o >>= 1) pm = fminf(pm, __shfl_down(pm, o));
    if ((threadIdx.x & 63) == 0) sred[threadIdx.x >> 6] = pm;
    __syncthreads();
    const float fill = fminf(fminf(sred[0], sred[1]), fminf(sred[2], sred[3]));

    const int tz = threadIdx.x & 3;
    const int tx = (threadIdx.x >> 2) & 7;
    const int ty = threadIdx.x >> 5;

    const int x  = blockIdx.y * 8 + tx;
    const int y  = yt * 8 + ty;
    const int zq = blockIdx.x * 16 + tz * 4;

    const double* c = cst + b * 12;
    const double c2 = c[2], c6 = c[6], c10 = c[10];
    const double dx = (double)x, dy = (double)y, dz = (double)zq;
    double ixd = fma(c[0], dx, fma(c[1], dy, fma(c2, dz, c[3])));
    double iyd = fma(c[4], dx, fma(c[5], dy, fma(c6, dz, c[7])));
    double izd = fma(c[8], dx, fma(c[9], dy, fma(c10, dz, c[11])));

    // exact per-k validity scan (sequential stepping, identical values to
    // the main loop, so no boundary-ulp disagreement)
    bool anyv = false;
    {
        double ax = ixd, ay = iyd, az = izd;
        #pragma unroll
        for (int k = 0; k < 4; k++) {
            anyv = anyv || ((ax >= 0.0) && (ax <= 159.0) && (ay >= 0.0) &&
                            (ay <= 159.0) && (az >= 0.0) && (az <= 159.0));
            ax += c2; ay += c6; az += c10;
        }
    }

    const float* base = img + (size_t)b * (HH * WW * DD);
    vfloat4 r;

    if (__any(anyv)) {
        #pragma unroll
        for (int k = 0; k < 4; k++) {
            const bool valid = (ixd >= 0.0) && (ixd <= 159.0) && (iyd >= 0.0) &&
                               (iyd <= 159.0) && (izd >= 0.0) && (izd <= 159.0);
            double flx = floor(ixd), fly = floor(iyd), flz = floor(izd);
            int x0 = (int)flx, y0 = (int)fly, z0 = (int)flz;
            // clamp for address safety; no-op for valid lanes
            x0 = min(max(x0, 0), 159);
            y0 = min(max(y0, 0), 159);
            z0 = min(max(z0, 0), 159);
            float fx = (float)(ixd - flx), fy = (float)(iyd - fly), fz = (float)(izd - flz);
            int x1 = min(x0 + 1, 159), y1 = min(y0 + 1, 159), z1 = min(z0 + 1, 159);
            // img[b, h=yi, w=xi, d=zi]
            const int o00 = (y0 * WW + x0) * DD;   // (y0, x0)
            const int o01 = (y0 * WW + x1) * DD;   // (y0, x1)
            const int o10 = (y1 * WW + x0) * DD;   // (y1, x0)
            const int o11 = (y1 * WW + x1) * DD;   // (y1, x1)
            float v000 = base[o00 + z0], v001 = base[o00 + z1];
            float v010 = base[o10 + z0], v011 = base[o10 + z1];
            float v100 = base[o01 + z0], v101 = base[o01 + z1];
            float v110 = base[o11 + z0], v111 = base[o11 + z1];
            float wx0 = 1.0f - fx, wx1 = fx;
            float wy0 = 1.0f - fy, wy1 = fy;
            float wz0 = 1.0f - fz, wz1 = fz;
            // accumulate in the reference's (ox, oy, oz) loop order
            float acc;
            acc  = ((wx0 * wy0) * wz0) * v000;
            acc += ((wx0 * wy0) * wz1) * v001;
            acc += ((wx0 * wy1) * wz0) * v010;
            acc += ((wx0 * wy1) * wz1) * v011;
            acc += ((wx1 * wy0) * wz0) * v100;
            acc += ((wx1 * wy0) * wz1) * v101;
            acc += ((wx1 * wy1) * wz0) * v110;
            acc += ((wx1 * wy1) * wz1) * v111;
            r[k] = valid ? acc : fill;
            ixd += c2; iyd += c6; izd += c10;
        }
    } else {
        r[0] = fill; r[1] = fill; r[2] = fill; r[3] = fill;
    }

    vfloat4* outp = (vfloat4*)(out + (size_t)((b * HH + y) * WW + x) * DD + zq);
    __builtin_nontemporal_store(r, outp);
}

extern "C" void kernel_launch(void* const* d_in, const int* in_sizes, int n_in,
                              void* d_out, int out_size, void* d_ws, size_t ws_size,
                              hipStream_t stream) {
    const float* img = (const float*)d_in[0];
    const float* transfos = (const float*)d_in[1];
    float* out = (float*)d_out;
    float* partial = (float*)d_ws;                      // 1024 floats
    double* cst = (double*)((char*)d_ws + 4096);        // 48 doubles

    min_cst_kernel<<<dim3(K1B, BB), 256, 0, stream>>>((const float4*)img, transfos,
                                                      partial, cst);
    st3d_kernel<<<dim3(DD / 16, WW / 8, (HH / 8) * BB), 256, 0, stream>>>(img, cst,
                                                                          partial, out);
}